// Round 1
// baseline (783.961 us; speedup 1.0000x reference)
//
#include <hip/hip_runtime.h>

#define N_NODE 50000
#define NEDGE  600000
#define SCAN_BLOCKS 196   // ceil(50000/256)

// ---------------- CSR build ----------------
// rel 0 = dd (dst=drug), 1 = gd (dst=drug), 2 = dg (dst=gene), 3 = gg (dst=gene)

__global__ __launch_bounds__(256) void k_count(
    const int* __restrict__ d0, const int* __restrict__ d1,
    const int* __restrict__ d2, const int* __restrict__ d3,
    int* __restrict__ cnt)
{
    int idx = blockIdx.x * 256 + threadIdx.x;
    if (idx >= 4 * NEDGE) return;
    int rel = idx / NEDGE;
    int e   = idx - rel * NEDGE;
    const int* dp = rel == 0 ? d0 : rel == 1 ? d1 : rel == 2 ? d2 : d3;
    atomicAdd(&cnt[rel * N_NODE + dp[e]], 1);
}

__global__ __launch_bounds__(256) void k_scanA(
    const int* __restrict__ cnt, int* __restrict__ off, int* __restrict__ bsum)
{
    int rel = blockIdx.x / SCAN_BLOCKS;
    int b   = blockIdx.x - rel * SCAN_BLOCKS;
    int i   = b * 256 + threadIdx.x;
    int v   = (i < N_NODE) ? cnt[rel * N_NODE + i] : 0;
    __shared__ int sh[256];
    sh[threadIdx.x] = v;
    __syncthreads();
    for (int d = 1; d < 256; d <<= 1) {
        int t = (threadIdx.x >= d) ? sh[threadIdx.x - d] : 0;
        __syncthreads();
        sh[threadIdx.x] += t;
        __syncthreads();
    }
    if (i < N_NODE) off[rel * (N_NODE + 1) + i] = sh[threadIdx.x] - v;  // block-local exclusive
    if (threadIdx.x == 255) bsum[rel * 200 + b] = sh[255];
}

__global__ __launch_bounds__(256) void k_scanB(int* __restrict__ bsum)
{
    int rel = blockIdx.x;
    int tid = threadIdx.x;
    int v = (tid < SCAN_BLOCKS) ? bsum[rel * 200 + tid] : 0;
    __shared__ int sh[256];
    sh[tid] = v;
    __syncthreads();
    for (int d = 1; d < 256; d <<= 1) {
        int t = (tid >= d) ? sh[tid - d] : 0;
        __syncthreads();
        sh[tid] += t;
        __syncthreads();
    }
    if (tid < SCAN_BLOCKS) bsum[rel * 200 + tid] = sh[tid] - v;  // exclusive over block sums
}

__global__ __launch_bounds__(256) void k_scanC(
    int* __restrict__ off, const int* __restrict__ bsum, int* __restrict__ cursor)
{
    int rel = blockIdx.x / SCAN_BLOCKS;
    int b   = blockIdx.x - rel * SCAN_BLOCKS;
    int i   = b * 256 + threadIdx.x;
    if (i < N_NODE) {
        int v = off[rel * (N_NODE + 1) + i] + bsum[rel * 200 + b];
        off[rel * (N_NODE + 1) + i] = v;
        cursor[rel * N_NODE + i]    = v;   // fill starts at segment base
    }
    if (b == 0 && threadIdx.x == 0) off[rel * (N_NODE + 1) + N_NODE] = NEDGE;
}

__global__ __launch_bounds__(256) void k_fill(
    const int* __restrict__ s0, const int* __restrict__ d0,
    const int* __restrict__ s1, const int* __restrict__ d1,
    const int* __restrict__ s2, const int* __restrict__ d2,
    const int* __restrict__ s3, const int* __restrict__ d3,
    int* __restrict__ cursor, int* __restrict__ edges)
{
    int idx = blockIdx.x * 256 + threadIdx.x;
    if (idx >= 4 * NEDGE) return;
    int rel = idx / NEDGE;
    int e   = idx - rel * NEDGE;
    const int* sp; const int* dp;
    switch (rel) {
        case 0: sp = s0; dp = d0; break;
        case 1: sp = s1; dp = d1; break;
        case 2: sp = s2; dp = d2; break;
        default: sp = s3; dp = d3; break;
    }
    int dst = dp[e];
    int p = atomicAdd(&cursor[rel * N_NODE + dst], 1);
    edges[rel * NEDGE + p] = sp[e];
}

// ---------------- fused dual-weight GEMM: out = X @ [Wa | Wb] ----------------
template <int K, int NOUT>
__global__ __launch_bounds__(256) void k_gemm_dual(
    const float* __restrict__ X, const float* __restrict__ Wa,
    const float* __restrict__ Wb, float* __restrict__ out, int M)
{
    constexpr int N    = NOUT / 2;
    constexpr int TXC  = NOUT / 4;   // thread-columns (4 cols each)
    constexpr int TYC  = 256 / TXC;  // row groups
    constexpr int ROWS = TYC * 4;    // rows per block
    __shared__ float Wc[K * NOUT];
    for (int i = threadIdx.x; i < K * NOUT; i += 256) {
        int k = i / NOUT, c = i - k * NOUT;
        Wc[i] = (c < N) ? Wa[k * N + c] : Wb[k * N + (c - N)];
    }
    __syncthreads();

    int tx = threadIdx.x % TXC, ty = threadIdx.x / TXC;
    int row0 = blockIdx.x * ROWS + ty * 4;
    int c0   = tx * 4;

    float acc[4][4] = {};
    const float* xr[4];
    bool rv[4];
#pragma unroll
    for (int i = 0; i < 4; i++) {
        int r = row0 + i;
        rv[i] = (r < M);
        xr[i] = X + (size_t)(rv[i] ? r : (M - 1)) * K;
    }

    for (int k = 0; k < K; k += 4) {
        float4 xv[4];
#pragma unroll
        for (int i = 0; i < 4; i++) xv[i] = *(const float4*)(xr[i] + k);
#pragma unroll
        for (int kk = 0; kk < 4; kk++) {
            float4 w = *(const float4*)&Wc[(k + kk) * NOUT + c0];
#pragma unroll
            for (int i = 0; i < 4; i++) {
                float xs = ((const float*)&xv[i])[kk];
                acc[i][0] += xs * w.x;
                acc[i][1] += xs * w.y;
                acc[i][2] += xs * w.z;
                acc[i][3] += xs * w.w;
            }
        }
    }
#pragma unroll
    for (int i = 0; i < 4; i++) {
        if (rv[i]) {
            *(float4*)(out + (size_t)(row0 + i) * NOUT + c0) =
                make_float4(acc[i][0], acc[i][1], acc[i][2], acc[i][3]);
        }
    }
}

// ---------------- segment-mean gathers ----------------
__device__ __forceinline__ float seg_sum64(
    const float* __restrict__ m, int ldm, int col,
    const int* __restrict__ off, const int* __restrict__ edges,
    int node, int lane, int* deg_out)
{
    int beg = off[node], end = off[node + 1];
    *deg_out = end - beg;
    float s = 0.f, s2 = 0.f;
    for (int e = beg; e < end; e += 64) {
        int nb = min(64, end - e);
        int eidx = (lane < nb) ? edges[e + lane] : 0;
        int j = 0;
        for (; j + 1 < nb; j += 2) {
            int sa = __shfl(eidx, j);
            int sb = __shfl(eidx, j + 1);
            s  += m[(size_t)sa * ldm + col + lane];
            s2 += m[(size_t)sb * ldm + col + lane];
        }
        if (j < nb) {
            int sa = __shfl(eidx, j);
            s += m[(size_t)sa * ldm + col + lane];
        }
    }
    return s + s2;
}

__global__ __launch_bounds__(256) void k_gather64(
    const float* __restrict__ mA, int colA, const float* __restrict__ mB, int colB,
    const int* __restrict__ offA, const int* __restrict__ eA,
    const int* __restrict__ offB, const int* __restrict__ eB,
    const float* __restrict__ bias, float* __restrict__ out, int ldm, int relu)
{
    int wid  = (blockIdx.x * 256 + threadIdx.x) >> 6;
    int lane = threadIdx.x & 63;
    if (wid >= N_NODE) return;
    int degA, degB;
    float sA = seg_sum64(mA, ldm, colA, offA, eA, wid, lane, &degA);
    float sB = seg_sum64(mB, ldm, colB, offB, eB, wid, lane, &degB);
    float h = sA / (float)max(degA, 1) + sB / (float)max(degB, 1) + bias[lane];
    if (relu) h = fmaxf(h, 0.f);
    out[(size_t)wid * 64 + lane] = h;
}

__device__ __forceinline__ float seg_sum32(
    const float* __restrict__ m, int ldm, int col,
    const int* __restrict__ off, const int* __restrict__ edges,
    int node, int lane, int* deg_out)
{
    int f = lane & 31, half = lane >> 5;
    int beg = off[node], end = off[node + 1];
    *deg_out = end - beg;
    float s = 0.f;
    for (int e = beg; e < end; e += 64) {
        int nb = min(64, end - e);
        int eidx = (lane < nb) ? edges[e + lane] : 0;
        for (int j = half; j < nb; j += 2) {
            int sa = __shfl(eidx, j);
            s += m[(size_t)sa * ldm + col + f];
        }
    }
    s += __shfl_xor(s, 32);
    return s;
}

__global__ __launch_bounds__(256) void k_gather32(
    const float* __restrict__ mA, int colA, const float* __restrict__ mB, int colB,
    const int* __restrict__ offA, const int* __restrict__ eA,
    const int* __restrict__ offB, const int* __restrict__ eB,
    const float* __restrict__ bias, float* __restrict__ out, int ldm)
{
    int wid  = (blockIdx.x * 256 + threadIdx.x) >> 6;
    int lane = threadIdx.x & 63;
    if (wid >= N_NODE) return;
    int f = lane & 31;
    int degA, degB;
    float sA = seg_sum32(mA, ldm, colA, offA, eA, wid, lane, &degA);
    float sB = seg_sum32(mB, ldm, colB, offB, eB, wid, lane, &degB);
    float h = sA / (float)max(degA, 1) + sB / (float)max(degB, 1) + bias[f];
    if (lane < 32) out[(size_t)wid * 32 + f] = h;
}

// ---------------- launcher ----------------
extern "C" void kernel_launch(void* const* d_in, const int* in_sizes, int n_in,
                              void* d_out, int out_size, void* d_ws, size_t ws_size,
                              hipStream_t stream)
{
    const float* xd = (const float*)d_in[0];
    const float* xg = (const float*)d_in[1];
    const int* dd_src = (const int*)d_in[2];  const int* dd_dst = (const int*)d_in[3];
    const int* dg_src = (const int*)d_in[4];  const int* dg_dst = (const int*)d_in[5];
    const int* gd_src = (const int*)d_in[6];  const int* gd_dst = (const int*)d_in[7];
    const int* gg_src = (const int*)d_in[8];  const int* gg_dst = (const int*)d_in[9];
    const float* W1dd = (const float*)d_in[10];
    const float* W1dg = (const float*)d_in[11];
    const float* W1gd = (const float*)d_in[12];
    const float* W1gg = (const float*)d_in[13];
    const float* b1d  = (const float*)d_in[14];
    const float* b1g  = (const float*)d_in[15];
    const float* W2dd = (const float*)d_in[16];
    const float* W2dg = (const float*)d_in[17];
    const float* W2gd = (const float*)d_in[18];
    const float* W2gg = (const float*)d_in[19];
    const float* b2d  = (const float*)d_in[20];
    const float* b2g  = (const float*)d_in[21];
    float* out = (float*)d_out;

    // workspace layout (~89 MB)
    int* cnt    = (int*)d_ws;                 // 4*50000
    int* cursor = cnt + 4 * N_NODE;           // 4*50000
    int* off    = cursor + 4 * N_NODE;        // 4*(50000+1)
    int* bsum   = off + 4 * (N_NODE + 1);     // 4*200
    int* edges  = bsum + 4 * 200;             // 4*600000
    float* md1  = (float*)(edges + 4 * NEDGE);        // 50000*128
    float* mg1  = md1 + (size_t)N_NODE * 128;         // 50000*128
    float* hd   = mg1 + (size_t)N_NODE * 128;         // 50000*64
    float* hg   = hd + (size_t)N_NODE * 64;           // 50000*64
    float* md2  = md1;  // layer-1 m dead after gather64 -> reuse
    float* mg2  = mg1;

    // ---- CSR build (shared by both layers) ----
    hipMemsetAsync(cnt, 0, 4 * N_NODE * sizeof(int), stream);
    k_count<<<(4 * NEDGE + 255) / 256, 256, 0, stream>>>(dd_dst, gd_dst, dg_dst, gg_dst, cnt);
    k_scanA<<<4 * SCAN_BLOCKS, 256, 0, stream>>>(cnt, off, bsum);
    k_scanB<<<4, 256, 0, stream>>>(bsum);
    k_scanC<<<4 * SCAN_BLOCKS, 256, 0, stream>>>(off, bsum, cursor);
    k_fill<<<(4 * NEDGE + 255) / 256, 256, 0, stream>>>(
        dd_src, dd_dst, gd_src, gd_dst, dg_src, dg_dst, gg_src, gg_dst, cursor, edges);

    const int* off_dd = off + 0 * (N_NODE + 1);
    const int* off_gd = off + 1 * (N_NODE + 1);
    const int* off_dg = off + 2 * (N_NODE + 1);
    const int* off_gg = off + 3 * (N_NODE + 1);
    const int* e_dd = edges + 0 * NEDGE;
    const int* e_gd = edges + 1 * NEDGE;
    const int* e_dg = edges + 2 * NEDGE;
    const int* e_gg = edges + 3 * NEDGE;

    // ---- layer 1: md1 = xd @ [W1dd|W1dg], mg1 = xg @ [W1gd|W1gg] ----
    k_gemm_dual<128, 128><<<(N_NODE + 31) / 32, 256, 0, stream>>>(xd, W1dd, W1dg, md1, N_NODE);
    k_gemm_dual<128, 128><<<(N_NODE + 31) / 32, 256, 0, stream>>>(xg, W1gd, W1gg, mg1, N_NODE);
    // hd = mean_dd(md1[:, :64]) + mean_gd(mg1[:, :64]) + b1d, relu
    k_gather64<<<(N_NODE * 64) / 256, 256, 0, stream>>>(
        md1, 0, mg1, 0, off_dd, e_dd, off_gd, e_gd, b1d, hd, 128, 1);
    // hg = mean_dg(md1[:, 64:]) + mean_gg(mg1[:, 64:]) + b1g, relu
    k_gather64<<<(N_NODE * 64) / 256, 256, 0, stream>>>(
        md1, 64, mg1, 64, off_dg, e_dg, off_gg, e_gg, b1g, hg, 128, 1);

    // ---- layer 2: md2 = hd @ [W2dd|W2dg], mg2 = hg @ [W2gd|W2gg] ----
    k_gemm_dual<64, 64><<<(N_NODE + 63) / 64, 256, 0, stream>>>(hd, W2dd, W2dg, md2, N_NODE);
    k_gemm_dual<64, 64><<<(N_NODE + 63) / 64, 256, 0, stream>>>(hg, W2gd, W2gg, mg2, N_NODE);
    // out rows [0, N_DRUG): drug embeddings
    k_gather32<<<(N_NODE * 64) / 256, 256, 0, stream>>>(
        md2, 0, mg2, 0, off_dd, e_dd, off_gd, e_gd, b2d, out, 64);
    // out rows [N_DRUG, N_DRUG+N_GENE): gene embeddings
    k_gather32<<<(N_NODE * 64) / 256, 256, 0, stream>>>(
        md2, 32, mg2, 32, off_dg, e_dg, off_gg, e_gg, b2g, out + (size_t)N_NODE * 32, 64);
}